// Round 16
// baseline (126.675 us; speedup 1.0000x reference)
//
#include <hip/hip_runtime.h>
#include <math.h>

#define IMGN (448*448)
#define DPI 3.14159265358979323846

typedef float2 cf;

__device__ __forceinline__ cf cmul(cf a, cf b){
    return make_float2(a.x*b.x - a.y*b.y, a.x*b.y + a.y*b.x);
}
__device__ __forceinline__ cf cadd(cf a, cf b){ return make_float2(a.x+b.x, a.y+b.y); }
__device__ __forceinline__ cf shflx(cf v, int m){
    return make_float2(__shfl_xor(v.x, m, 64), __shfl_xor(v.y, m, 64));
}
__device__ __forceinline__ int bitrev6(int l){ return (int)(__brev((unsigned)l) >> 26); }

// Generate the 448-entry twiddle table in LDS: WtL[t] = exp(-2*pi*i*t/448).
__device__ __forceinline__ void gen_Wt(cf* WtL, int tid, int nthr){
    for(int t = tid; t < 448; t += nthr){
        float sv, cv;
        __sincosf((-6.2831853071795865f/448.f) * (float)t, &sv, &cv);
        WtL[t] = make_float2(cv, sv);
    }
}

// Compile-time 7th roots of unity: w7(m) = exp(-2*pi*i*m/7).
__device__ __forceinline__ cf w7(int m){
    const float cr[7] = { 1.f,  0.62348980185873353f, -0.22252093395631440f,
                         -0.90096886790241913f, -0.90096886790241913f,
                         -0.22252093395631440f,  0.62348980185873353f };
    const float ci[7] = { 0.f, -0.78183148246802981f, -0.97492791218182361f,
                         -0.43388373911755812f,  0.43388373911755812f,
                          0.97492791218182361f,  0.78183148246802981f };
    return make_float2(cr[m], ci[m]);
}

// ---------------- FFT-448 per wave: lane n1 holds x[n1 + 64*n2], n2 = reg 0..6.
// Forward output: reg j, lane L  <->  X[j + 7*bitrev6(L)]
__device__ void fft448_fwd(cf* c, int lane, const cf* __restrict__ Wt){
    cf y[7];
#pragma unroll
    for(int k2=0;k2<7;k2++){
        cf acc = c[0];
#pragma unroll
        for(int n2=1;n2<7;n2++){
            acc = cadd(acc, cmul(c[n2], w7((n2*k2) % 7)));
        }
        y[k2] = acc;
    }
    c[0] = y[0];
#pragma unroll
    for(int k2=1;k2<7;k2++) c[k2] = cmul(y[k2], Wt[(lane*k2) % 448]);
#pragma unroll
    for(int h=32; h>=1; h>>=1){
        int t7 = (lane & (h-1)) * (32/h) * 7;
        cf w = Wt[t7];
        bool up = (lane & h) != 0;
#pragma unroll
        for(int j=0;j<7;j++){
            cf o = shflx(c[j], h);
            cf d = make_float2(o.x - c[j].x, o.y - c[j].y);
            cf s = make_float2(c[j].x + o.x, c[j].y + o.y);
            c[j] = up ? cmul(d, w) : s;
        }
    }
}

// Inverse: input layout = forward output layout; output: lane n1 holds x[n1+64*n2]; scaled 1/448.
__device__ void fft448_inv(cf* c, int lane, const cf* __restrict__ Wt){
#pragma unroll
    for(int h=1; h<=32; h<<=1){
        int t7 = (lane & (h-1)) * (32/h) * 7;
        cf w = Wt[t7]; w.y = -w.y;   // conj
        bool up = (lane & h) != 0;
#pragma unroll
        for(int j=0;j<7;j++){
            cf m = up ? cmul(c[j], w) : c[j];
            cf o = shflx(m, h);
            c[j] = up ? make_float2(o.x - m.x, o.y - m.y)
                      : make_float2(m.x + o.x, m.y + o.y);
        }
    }
#pragma unroll
    for(int k2=1;k2<7;k2++){
        cf w = Wt[(lane*k2) % 448]; w.y = -w.y;
        c[k2] = cmul(c[k2], w);
    }
    cf out[7];
#pragma unroll
    for(int n2=0;n2<7;n2++){
        cf acc = c[0];
#pragma unroll
        for(int k2=1;k2<7;k2++){
            cf w = w7((n2*k2) % 7); w.y = -w.y;   // conj, compile-time
            acc = cadd(acc, cmul(c[k2], w));
        }
        out[n2] = make_float2(acc.x * (1.0f/448.0f), acc.y * (1.0f/448.0f));
    }
#pragma unroll
    for(int j=0;j<7;j++) c[j] = out[j];
}

// Packed two-real-rows path: c = FFT(a + i*b). Unpack A,B (Hermitian halves),
// apply per-row phases for shift (sa+oa),(sb+ob), repack Z' = A' + i*B'.
// Non-Nyquist bins: summed phase (exact). Nyquist (k=-224): cos(pi*s)*cos(pi*o),
// matching the reference's Re-projection placement.
__device__ void unpack_phase_repack(cf* c, int lane, float sa, float sb, float oa, float ob){
    int b6 = bitrev6(lane);
    int L0 = bitrev6((64 - b6) & 63);
    cf zm[7];
    zm[0] = make_float2(__shfl(c[0].x, L0, 64), __shfl(c[0].y, L0, 64));
#pragma unroll
    for(int j=1;j<7;j++)
        zm[j] = make_float2(__shfl(c[7-j].x, 63-lane, 64), __shfl(c[7-j].y, 63-lane, 64));
    float ua = (sa+oa)*(1.0f/448.0f), ub = (sb+ob)*(1.0f/448.0f);
#pragma unroll
    for(int j=0;j<7;j++){
        cf Zk = c[j], m = zm[j];
        cf Av = make_float2(0.5f*(Zk.x + m.x), 0.5f*(Zk.y - m.y));
        cf Bv = make_float2(0.5f*(Zk.y + m.y), 0.5f*(m.x - Zk.x));
        int k = j + 7*b6;
        int kk = (k < 224) ? k : k - 448;
        float pax, pay, pbx, pby;
        if (j == 0 && kk == -224){
            float u = 0.5f*sa; u -= rintf(u);
            float v = 0.5f*oa; v -= rintf(v);
            pax = __cosf(6.2831853071795865f*u) * __cosf(6.2831853071795865f*v); pay = 0.f;
            u = 0.5f*sb; u -= rintf(u);
            v = 0.5f*ob; v -= rintf(v);
            pbx = __cosf(6.2831853071795865f*u) * __cosf(6.2831853071795865f*v); pby = 0.f;
        } else {
            float t = (float)kk*ua; t -= rintf(t);
            __sincosf(-6.2831853071795865f*t, &pay, &pax);
            t = (float)kk*ub; t -= rintf(t);
            __sincosf(-6.2831853071795865f*t, &pby, &pbx);
        }
        cf Ap = cmul(Av, make_float2(pax, pay));
        cf Bp = cmul(Bv, make_float2(pbx, pby));
        c[j] = make_float2(Ap.x - Bp.y, Ap.y + Bp.x);
    }
}

// Precompute packed row spectra of img2: wave rp -> rows 2rp,2rp+1. S2[rp][j*64+lane].
__global__ void __launch_bounds__(256) k_prefft(
        const float* __restrict__ img2, cf* __restrict__ S2){
    __shared__ cf WtL[448];
    gen_Wt(WtL, threadIdx.x, 256);
    __syncthreads();
    int wid = (int)((blockIdx.x*blockDim.x + threadIdx.x) >> 6);
    int lane = threadIdx.x & 63;
    if (wid >= 224) return;
    const float* ra = img2 + (long)(2*wid)*448;
    cf c[7];
#pragma unroll
    for(int m=0;m<7;m++) c[m] = make_float2(ra[lane + 64*m], ra[448 + lane + 64*m]);
    fft448_fwd(c, lane, WtL);
    cf* dp = S2 + (long)wid*448;
#pragma unroll
    for(int j=0;j<7;j++) dp[j*64 + lane] = c[j];
}

// Pass 1 (row shear, packed, spectrum reused): wave -> (rl, row-pair rp).
// mode=1 (final SxA): per-block FINISH prologue -- reduce partial[525][15] + argmin +
// parabolic refinement computed redundantly by every block (deterministic, identical);
// block 0 writes prm/outv to global for the downstream F2-F4 kernels.
__global__ void __launch_bounds__(256) k_pass1(
        const cf* __restrict__ S2, float* __restrict__ A,
        int nrot, int rotBase, float* __restrict__ prm, int mode,
        const float* __restrict__ partial, float* __restrict__ outv){
    __shared__ cf WtL[448];
    __shared__ float sadL[525];
    __shared__ float wvv[4];
    __shared__ int   wii[4];
    __shared__ float prmL[3];
    int tid = threadIdx.x;
    gen_Wt(WtL, tid, 256);
    int w = tid >> 6, lane = tid & 63;
    if (mode){
        float v = 3.4e38f; int idx = 0;
        for(int cb = tid; cb < 525; cb += 256){
            const float* p = partial + (long)cb*15;
            float s = 0.f;
#pragma unroll
            for(int i=0;i<15;i++) s += p[i];
            s *= (1.f/162409.0f);
            sadL[cb] = s;
            if (s < v){ v = s; idx = cb; }
        }
#pragma unroll
        for(int d=32; d>=1; d>>=1){
            float ov = __shfl_xor(v, d, 64);
            int   oi = __shfl_xor(idx, d, 64);
            if (ov < v || (ov == v && oi < idx)){ v = ov; idx = oi; }
        }
        if (lane == 0){ wvv[w] = v; wii[w] = idx; }
        __syncthreads();
        if (tid == 0){
            float bv = wvv[0]; int best = wii[0];
            for(int q=1;q<4;q++){
                if (wvv[q] < bv || (wvv[q] == bv && wii[q] < best)){ bv = wvv[q]; best = wii[q]; }
            }
            int i = best/105, j = (best/21)%5, k = best%21;
            float p0,p1,p2,aa,bb,dx,dy,dr;
            p0 = sadL[(((i+4)%5)*5 + j)*21 + k]; p1 = sadL[(i*5+j)*21+k]; p2 = sadL[(((i+1)%5)*5 + j)*21 + k];
            aa = (p0+p2)*0.5f - p1; bb = (p2-p0)*0.5f; dx = -bb/(2.f*aa);
            p0 = sadL[(i*5 + (j+4)%5)*21 + k]; p2 = sadL[(i*5 + (j+1)%5)*21 + k];
            aa = (p0+p2)*0.5f - p1; bb = (p2-p0)*0.5f; dy = -bb/(2.f*aa);
            p0 = sadL[(i*5+j)*21 + (k+20)%21]; p2 = sadL[(i*5+j)*21 + (k+1)%21];
            aa = (p0+p2)*0.5f - p1; bb = (p2-p0)*0.5f; dr = -bb/(2.f*aa);
            float sx = (float)(i-2) + dx;
            float sy = (float)(j-2) + dy;
            float rot = ((float)(k-10) + dr) * (float)(DPI/180.0);
            prmL[0] = -sx; prmL[1] = -sy; prmL[2] = -rot;
            if (blockIdx.x == 0){
                outv[0] = sx; outv[1] = sy; outv[2] = rot;
                prm[0] = -sx; prm[1] = -sy; prm[2] = -rot;
            }
        }
        __syncthreads();
    } else {
        __syncthreads();
    }
    int wid = (int)((blockIdx.x*blockDim.x + threadIdx.x) >> 6);
    if (wid >= nrot*224) return;
    int rl = wid / 224, rp = wid % 224;
    float a;
    if (mode) a = (float)(-tan((double)prmL[2]*0.5));
    else {
        float th = ((float)(rotBase+rl) - 10.f) * 0.017453292519943295f;
        a = -tanf(0.5f*th);
    }
    float sa = a * ((float)(2*rp) - 223.5f);
    float sb = a * ((float)(2*rp+1) - 223.5f);
    const cf* sp = S2 + (long)rp*448;
    cf c[7];
#pragma unroll
    for(int j=0;j<7;j++) c[j] = sp[j*64 + lane];
    unpack_phase_repack(c, lane, sa, sb, 0.f, 0.f);
    fft448_inv(c, lane, WtL);
    float* da = A + (long)rl*IMGN + (long)(2*rp)*448;
#pragma unroll
    for(int m=0;m<7;m++){ da[lane + 64*m] = c[m].x; da[448 + lane + 64*m] = c[m].y; }
}

// Pass 2 (col pass, packed): 512-thr block = 8 waves, 16 columns (8 pairs) of one image.
// mode=0: grid shear. mode=1: final Sy, b=sin(prm[2]). mode=2: final Ty (b=0, be=prm[1]).
__global__ void __launch_bounds__(512) k_pass2col(
        const float* __restrict__ src, float* __restrict__ dst,
        int rotBase, const float* __restrict__ prm, int mode){
    __shared__ float tile[448][17];
    __shared__ cf WtL[448];
    int tid = threadIdx.x;
    gen_Wt(WtL, tid, 512);
    int rl = blockIdx.x / 28, grp = blockIdx.x % 28;
    int c0 = grp * 16;
    const float* sp = src + (long)rl*IMGN;
#pragma unroll
    for(int i=0;i<14;i++){
        int e = i*512 + tid;
        int r = e >> 4, cc = e & 15;
        tile[r][cc] = sp[(long)r*448 + c0 + cc];
    }
    __syncthreads();
    int w = tid >> 6, lane = tid & 63;
    int ca = c0 + 2*w;
    float b, be;
    if (mode == 1){ b = (float)sin((double)prm[2]); be = 0.f; }
    else if (mode == 2){ b = 0.f; be = prm[1]; }
    else {
        float th = ((float)(rotBase+rl) - 10.f) * 0.017453292519943295f;
        b = sinf(th); be = 0.f;
    }
    float sa = b * ((float)ca - 223.5f) + be;
    float sb = b * ((float)(ca+1) - 223.5f) + be;
    cf c[7];
#pragma unroll
    for(int m=0;m<7;m++){
        int n = lane + 64*m;
        c[m] = make_float2(tile[n][2*w], tile[n][2*w+1]);
    }
    fft448_fwd(c, lane, WtL);
    unpack_phase_repack(c, lane, sa, sb, 0.f, 0.f);
    fft448_inv(c, lane, WtL);
#pragma unroll
    for(int m=0;m<7;m++){
        int n = lane + 64*m;
        tile[n][2*w] = c[m].x; tile[n][2*w+1] = c[m].y;
    }
    __syncthreads();
    float* dp = dst + (long)rl*IMGN;
#pragma unroll
    for(int i=0;i<14;i++){
        int e = i*512 + tid;
        int r = e >> 4, cc = e & 15;
        dp[(long)r*448 + c0 + cc] = tile[r][cc];
    }
}

// Pass 3 (row shear, packed, fresh fwd) -- FINAL WARP ONLY (mode=1 path used).
// mode=1: final SxB with Tx folded (same-axis): non-Nyq summed phase; Nyquist cos*cos.
__global__ void __launch_bounds__(256) k_pass3(
        const float* __restrict__ B, float* __restrict__ A,
        int nrot, int rotBase, const float* __restrict__ prm, int mode){
    __shared__ cf WtL[448];
    gen_Wt(WtL, threadIdx.x, 256);
    __syncthreads();
    int wid = (int)((blockIdx.x*blockDim.x + threadIdx.x) >> 6);
    int lane = threadIdx.x & 63;
    if (wid >= nrot*224) return;
    int rl = wid / 224, rp = wid % 224;
    float a, ga;
    if (mode){ a = (float)(-tan((double)prm[2]*0.5)); ga = prm[0]; }
    else {
        float th = ((float)(rotBase+rl) - 10.f) * 0.017453292519943295f;
        a = -tanf(0.5f*th); ga = 0.f;
    }
    float sa = a * ((float)(2*rp) - 223.5f);
    float sb = a * ((float)(2*rp+1) - 223.5f);
    const float* ra = B + (long)rl*IMGN + (long)(2*rp)*448;
    cf c[7];
#pragma unroll
    for(int m=0;m<7;m++) c[m] = make_float2(ra[lane + 64*m], ra[448 + lane + 64*m]);
    fft448_fwd(c, lane, WtL);
    unpack_phase_repack(c, lane, sa, sb, ga, ga);
    fft448_inv(c, lane, WtL);
    float* da = A + (long)rl*IMGN + (long)(2*rp)*448;
#pragma unroll
    for(int m=0;m<7;m++){ da[lane + 64*m] = c[m].x; da[448 + lane + 64*m] = c[m].y; }
}

// Fused pass3 + SAD. Block = 1024 thr (16 waves) handles one (rotation rl, 28-row output tile tt).
// Computes R rows base..base+31 (base = 20+28*tt) via packed row shear into LDS,
// then SAD for output rows 22+28*tt .. min(+27, 424) against img1 with 25 integer rolls.
// partial[combo*15 + tt]; combo = (ix*5 + jy)*21 + rot.
__global__ void __launch_bounds__(1024) k_pass3sad(
        const float* __restrict__ B, const float* __restrict__ img1,
        float* __restrict__ partial, int nrot, int rotBase){
    __shared__ float tile[32][448];
    __shared__ cf WtL[448];
    __shared__ float csum[16][25];
    int tid = threadIdx.x;
    gen_Wt(WtL, tid, 1024);
    int w = tid >> 6, lane = tid & 63;
    int bid = blockIdx.x;
    int rl = bid / 15, tt = bid % 15;
    int base = 20 + 28*tt;
    float th = ((float)(rotBase+rl) - 10.f) * 0.017453292519943295f;
    float a = -tanf(0.5f*th);
    int rrow = base + 2*w;
    float sa = a * ((float)rrow - 223.5f);
    float sb = a * ((float)(rrow+1) - 223.5f);
    const float* ra = B + (long)rl*IMGN + (long)rrow*448;
    cf c[7];
#pragma unroll
    for(int m=0;m<7;m++) c[m] = make_float2(ra[lane + 64*m], ra[448 + lane + 64*m]);
    __syncthreads();   // WtL ready
    fft448_fwd(c, lane, WtL);
    unpack_phase_repack(c, lane, sa, sb, 0.f, 0.f);
    fft448_inv(c, lane, WtL);
#pragma unroll
    for(int m=0;m<7;m++){
        tile[2*w][lane + 64*m]   = c[m].x;
        tile[2*w+1][lane + 64*m] = c[m].y;
    }
    __syncthreads();
    float acc[25];
#pragma unroll
    for(int q=0;q<25;q++) acc[q] = 0.f;
    int cpos[7];
#pragma unroll
    for(int m=0;m<7;m++) cpos[m] = 22 + lane + 64*m;
#pragma unroll
    for(int pass=0; pass<2; pass++){
        int q = pass*16 + w;
        if (q < 28){
            int r = 22 + 28*tt + q;
            if (r <= 424){
                float iv[7];
#pragma unroll
                for(int m=0;m<7;m++)
                    iv[m] = (cpos[m] < 425) ? img1[(long)r*448 + cpos[m]] : 0.f;
#pragma unroll
                for(int jy=0;jy<5;jy++){
                    const float* Rrow = tile[r - (jy-2) - base];
#pragma unroll
                    for(int ix=0;ix<5;ix++){
                        float s2 = 0.f;
#pragma unroll
                        for(int m=0;m<7;m++){
                            if (cpos[m] < 425) s2 += fabsf(iv[m] - Rrow[cpos[m] - (ix-2)]);
                        }
                        acc[ix*5 + jy] += s2;
                    }
                }
            }
        }
    }
#pragma unroll
    for(int q=0;q<25;q++){
        float v = acc[q];
#pragma unroll
        for(int d=32; d>=1; d>>=1) v += __shfl_xor(v, d, 64);
        if (lane == 0) csum[w][q] = v;
    }
    __syncthreads();
    if (tid < 25){
        float s = 0.f;
#pragma unroll
        for(int ww=0; ww<16; ww++) s += csum[ww][tid];
        int ix = tid/5, jy = tid%5;
        int combo = (ix*5 + jy)*21 + (rotBase + rl);
        partial[(long)combo*15 + tt] = s;
    }
}

extern "C" void kernel_launch(void* const* d_in, const int* in_sizes, int n_in,
                              void* d_out, int out_size, void* d_ws, size_t ws_size,
                              hipStream_t stream){
    const float* img1 = (const float*)d_in[0];
    const float* img2 = (const float*)d_in[1];
    float* out = (float*)d_out;
    char* ws = (char*)d_ws;

    size_t off = 0;
    float* prm = (float*)(ws + off); off += 256;
    float* partial = (float*)(ws + off); off += (size_t)525*15*sizeof(float);
    off = (off + 255) & ~(size_t)255;
    cf* S2 = (cf*)(ws + off); off += (size_t)224*448*sizeof(cf);
    off = (off + 255) & ~(size_t)255;

    size_t slot = (size_t)IMGN * sizeof(float);
    size_t remain = (ws_size > off) ? (ws_size - off) : 0;
    int NB = (int)(remain / (2*slot));
    if (NB > 21) NB = 21;
    if (NB < 2) NB = 2;
    float* A = (float*)(ws + off);
    float* B = (float*)(ws + off + (size_t)NB*slot);

    auto blocks = [](long waves){ return dim3((unsigned)((waves*64 + 255)/256)); };

    hipLaunchKernelGGL(k_prefft, dim3(56), dim3(256), 0, stream, img2, S2);

    for(int rb = 0; rb < 21; rb += NB){
        int nr = (21 - rb < NB) ? (21 - rb) : NB;
        hipLaunchKernelGGL(k_pass1, blocks((long)nr*224), dim3(256), 0, stream,
                           (const cf*)S2, A, nr, rb, prm, 0, (const float*)partial, out);
        hipLaunchKernelGGL(k_pass2col, dim3(nr*28), dim3(512), 0, stream,
                           A, B, rb, prm, 0);
        hipLaunchKernelGGL(k_pass3sad, dim3(nr*15), dim3(1024), 0, stream,
                           B, img1, partial, nr, rb);
    }

    // Final sub-pixel warp, 4 packed passes (F1 fuses the finish reduce/argmin):
    //   out = Ty(prm[1]) o [Sx(a*yy) + Tx-fold(prm[0])] o Sy(b*xx) o Sx(a*yy)  on img2
    hipLaunchKernelGGL(k_pass1, blocks(224), dim3(256), 0, stream,
                       (const cf*)S2, A, 1, 0, prm, 1, (const float*)partial, out);
    hipLaunchKernelGGL(k_pass2col, dim3(28), dim3(512), 0, stream,
                       A, B, 0, prm, 1);
    hipLaunchKernelGGL(k_pass3, blocks(224), dim3(256), 0, stream,
                       B, A, 1, 0, prm, 1);
    hipLaunchKernelGGL(k_pass2col, dim3(28), dim3(512), 0, stream,
                       A, out + 3, 0, prm, 2);
}

// Round 17
// 114.097 us; speedup vs baseline: 1.1102x; 1.1102x over previous
//
#include <hip/hip_runtime.h>
#include <math.h>

#define IMGN (448*448)
#define DPI 3.14159265358979323846

typedef float2 cf;

__device__ __forceinline__ cf cmul(cf a, cf b){
    return make_float2(a.x*b.x - a.y*b.y, a.x*b.y + a.y*b.x);
}
__device__ __forceinline__ cf cadd(cf a, cf b){ return make_float2(a.x+b.x, a.y+b.y); }
__device__ __forceinline__ cf shflx(cf v, int m){
    return make_float2(__shfl_xor(v.x, m, 64), __shfl_xor(v.y, m, 64));
}
__device__ __forceinline__ int bitrev6(int l){ return (int)(__brev((unsigned)l) >> 26); }

// Generate the 448-entry twiddle table in LDS: WtL[t] = exp(-2*pi*i*t/448).
__device__ __forceinline__ void gen_Wt(cf* WtL, int tid, int nthr){
    for(int t = tid; t < 448; t += nthr){
        float sv, cv;
        __sincosf((-6.2831853071795865f/448.f) * (float)t, &sv, &cv);
        WtL[t] = make_float2(cv, sv);
    }
}

// Compile-time 7th roots of unity: w7(m) = exp(-2*pi*i*m/7).
__device__ __forceinline__ cf w7(int m){
    const float cr[7] = { 1.f,  0.62348980185873353f, -0.22252093395631440f,
                         -0.90096886790241913f, -0.90096886790241913f,
                         -0.22252093395631440f,  0.62348980185873353f };
    const float ci[7] = { 0.f, -0.78183148246802981f, -0.97492791218182361f,
                         -0.43388373911755812f,  0.43388373911755812f,
                          0.97492791218182361f,  0.78183148246802981f };
    return make_float2(cr[m], ci[m]);
}

// ---------------- FFT-448 per wave: lane n1 holds x[n1 + 64*n2], n2 = reg 0..6.
// Forward output: reg j, lane L  <->  X[j + 7*bitrev6(L)]
__device__ void fft448_fwd(cf* c, int lane, const cf* __restrict__ Wt){
    cf y[7];
#pragma unroll
    for(int k2=0;k2<7;k2++){
        cf acc = c[0];
#pragma unroll
        for(int n2=1;n2<7;n2++){
            acc = cadd(acc, cmul(c[n2], w7((n2*k2) % 7)));
        }
        y[k2] = acc;
    }
    c[0] = y[0];
#pragma unroll
    for(int k2=1;k2<7;k2++) c[k2] = cmul(y[k2], Wt[(lane*k2) % 448]);
#pragma unroll
    for(int h=32; h>=1; h>>=1){
        int t7 = (lane & (h-1)) * (32/h) * 7;
        cf w = Wt[t7];
        bool up = (lane & h) != 0;
#pragma unroll
        for(int j=0;j<7;j++){
            cf o = shflx(c[j], h);
            cf d = make_float2(o.x - c[j].x, o.y - c[j].y);
            cf s = make_float2(c[j].x + o.x, c[j].y + o.y);
            c[j] = up ? cmul(d, w) : s;
        }
    }
}

// Inverse: input layout = forward output layout; output: lane n1 holds x[n1+64*n2]; scaled 1/448.
__device__ void fft448_inv(cf* c, int lane, const cf* __restrict__ Wt){
#pragma unroll
    for(int h=1; h<=32; h<<=1){
        int t7 = (lane & (h-1)) * (32/h) * 7;
        cf w = Wt[t7]; w.y = -w.y;   // conj
        bool up = (lane & h) != 0;
#pragma unroll
        for(int j=0;j<7;j++){
            cf m = up ? cmul(c[j], w) : c[j];
            cf o = shflx(m, h);
            c[j] = up ? make_float2(o.x - m.x, o.y - m.y)
                      : make_float2(m.x + o.x, m.y + o.y);
        }
    }
#pragma unroll
    for(int k2=1;k2<7;k2++){
        cf w = Wt[(lane*k2) % 448]; w.y = -w.y;
        c[k2] = cmul(c[k2], w);
    }
    cf out[7];
#pragma unroll
    for(int n2=0;n2<7;n2++){
        cf acc = c[0];
#pragma unroll
        for(int k2=1;k2<7;k2++){
            cf w = w7((n2*k2) % 7); w.y = -w.y;   // conj, compile-time
            acc = cadd(acc, cmul(c[k2], w));
        }
        out[n2] = make_float2(acc.x * (1.0f/448.0f), acc.y * (1.0f/448.0f));
    }
#pragma unroll
    for(int j=0;j<7;j++) c[j] = out[j];
}

// Packed two-real-rows path: c = FFT(a + i*b). Unpack A,B (Hermitian halves),
// apply per-row phases for shift (sa+oa),(sb+ob), repack Z' = A' + i*B'.
// Non-Nyquist bins: summed phase (exact). Nyquist (k=-224): cos(pi*s)*cos(pi*o),
// matching the reference's Re-projection placement.
__device__ void unpack_phase_repack(cf* c, int lane, float sa, float sb, float oa, float ob){
    int b6 = bitrev6(lane);
    int L0 = bitrev6((64 - b6) & 63);
    cf zm[7];
    zm[0] = make_float2(__shfl(c[0].x, L0, 64), __shfl(c[0].y, L0, 64));
#pragma unroll
    for(int j=1;j<7;j++)
        zm[j] = make_float2(__shfl(c[7-j].x, 63-lane, 64), __shfl(c[7-j].y, 63-lane, 64));
    float ua = (sa+oa)*(1.0f/448.0f), ub = (sb+ob)*(1.0f/448.0f);
#pragma unroll
    for(int j=0;j<7;j++){
        cf Zk = c[j], m = zm[j];
        cf Av = make_float2(0.5f*(Zk.x + m.x), 0.5f*(Zk.y - m.y));
        cf Bv = make_float2(0.5f*(Zk.y + m.y), 0.5f*(m.x - Zk.x));
        int k = j + 7*b6;
        int kk = (k < 224) ? k : k - 448;
        float pax, pay, pbx, pby;
        if (j == 0 && kk == -224){
            float u = 0.5f*sa; u -= rintf(u);
            float v = 0.5f*oa; v -= rintf(v);
            pax = __cosf(6.2831853071795865f*u) * __cosf(6.2831853071795865f*v); pay = 0.f;
            u = 0.5f*sb; u -= rintf(u);
            v = 0.5f*ob; v -= rintf(v);
            pbx = __cosf(6.2831853071795865f*u) * __cosf(6.2831853071795865f*v); pby = 0.f;
        } else {
            float t = (float)kk*ua; t -= rintf(t);
            __sincosf(-6.2831853071795865f*t, &pay, &pax);
            t = (float)kk*ub; t -= rintf(t);
            __sincosf(-6.2831853071795865f*t, &pby, &pbx);
        }
        cf Ap = cmul(Av, make_float2(pax, pay));
        cf Bp = cmul(Bv, make_float2(pbx, pby));
        c[j] = make_float2(Ap.x - Bp.y, Ap.y + Bp.x);
    }
}

// Precompute packed row spectra of img2: wave rp -> rows 2rp,2rp+1. S2[rp][j*64+lane].
__global__ void __launch_bounds__(256) k_prefft(
        const float* __restrict__ img2, cf* __restrict__ S2){
    __shared__ cf WtL[448];
    gen_Wt(WtL, threadIdx.x, 256);
    __syncthreads();
    int wid = (int)((blockIdx.x*blockDim.x + threadIdx.x) >> 6);
    int lane = threadIdx.x & 63;
    if (wid >= 224) return;
    const float* ra = img2 + (long)(2*wid)*448;
    cf c[7];
#pragma unroll
    for(int m=0;m<7;m++) c[m] = make_float2(ra[lane + 64*m], ra[448 + lane + 64*m]);
    fft448_fwd(c, lane, WtL);
    cf* dp = S2 + (long)wid*448;
#pragma unroll
    for(int j=0;j<7;j++) dp[j*64 + lane] = c[j];
}

// Pass 1 (row shear, packed, spectrum reused): wave -> (rl, row-pair rp).
// mode=1 (final SxA): per-block FINISH prologue -- reduce partial[525][34] + argmin +
// parabolic refinement computed redundantly by every block (deterministic, identical);
// block 0 writes prm/outv to global for the downstream F2-F4 kernels.
__global__ void __launch_bounds__(256) k_pass1(
        const cf* __restrict__ S2, float* __restrict__ A,
        int nrot, int rotBase, float* __restrict__ prm, int mode,
        const float* __restrict__ partial, float* __restrict__ outv){
    __shared__ cf WtL[448];
    __shared__ float sadL[525];
    __shared__ float wvv[4];
    __shared__ int   wii[4];
    __shared__ float prmL[3];
    int tid = threadIdx.x;
    gen_Wt(WtL, tid, 256);
    int w = tid >> 6, lane = tid & 63;
    if (mode){
        float v = 3.4e38f; int idx = 0;
        for(int cb = tid; cb < 525; cb += 256){
            const float* p = partial + (long)cb*34;
            float s = 0.f;
#pragma unroll
            for(int i=0;i<34;i++) s += p[i];
            s *= (1.f/162409.0f);
            sadL[cb] = s;
            if (s < v){ v = s; idx = cb; }
        }
#pragma unroll
        for(int d=32; d>=1; d>>=1){
            float ov = __shfl_xor(v, d, 64);
            int   oi = __shfl_xor(idx, d, 64);
            if (ov < v || (ov == v && oi < idx)){ v = ov; idx = oi; }
        }
        if (lane == 0){ wvv[w] = v; wii[w] = idx; }
        __syncthreads();
        if (tid == 0){
            float bv = wvv[0]; int best = wii[0];
            for(int q=1;q<4;q++){
                if (wvv[q] < bv || (wvv[q] == bv && wii[q] < best)){ bv = wvv[q]; best = wii[q]; }
            }
            int i = best/105, j = (best/21)%5, k = best%21;
            float p0,p1,p2,aa,bb,dx,dy,dr;
            p0 = sadL[(((i+4)%5)*5 + j)*21 + k]; p1 = sadL[(i*5+j)*21+k]; p2 = sadL[(((i+1)%5)*5 + j)*21 + k];
            aa = (p0+p2)*0.5f - p1; bb = (p2-p0)*0.5f; dx = -bb/(2.f*aa);
            p0 = sadL[(i*5 + (j+4)%5)*21 + k]; p2 = sadL[(i*5 + (j+1)%5)*21 + k];
            aa = (p0+p2)*0.5f - p1; bb = (p2-p0)*0.5f; dy = -bb/(2.f*aa);
            p0 = sadL[(i*5+j)*21 + (k+20)%21]; p2 = sadL[(i*5+j)*21 + (k+1)%21];
            aa = (p0+p2)*0.5f - p1; bb = (p2-p0)*0.5f; dr = -bb/(2.f*aa);
            float sx = (float)(i-2) + dx;
            float sy = (float)(j-2) + dy;
            float rot = ((float)(k-10) + dr) * (float)(DPI/180.0);
            prmL[0] = -sx; prmL[1] = -sy; prmL[2] = -rot;
            if (blockIdx.x == 0){
                outv[0] = sx; outv[1] = sy; outv[2] = rot;
                prm[0] = -sx; prm[1] = -sy; prm[2] = -rot;
            }
        }
        __syncthreads();
    } else {
        __syncthreads();
    }
    int wid = (int)((blockIdx.x*blockDim.x + threadIdx.x) >> 6);
    if (wid >= nrot*224) return;
    int rl = wid / 224, rp = wid % 224;
    float a;
    if (mode) a = (float)(-tan((double)prmL[2]*0.5));
    else {
        float th = ((float)(rotBase+rl) - 10.f) * 0.017453292519943295f;
        a = -tanf(0.5f*th);
    }
    float sa = a * ((float)(2*rp) - 223.5f);
    float sb = a * ((float)(2*rp+1) - 223.5f);
    const cf* sp = S2 + (long)rp*448;
    cf c[7];
#pragma unroll
    for(int j=0;j<7;j++) c[j] = sp[j*64 + lane];
    unpack_phase_repack(c, lane, sa, sb, 0.f, 0.f);
    fft448_inv(c, lane, WtL);
    float* da = A + (long)rl*IMGN + (long)(2*rp)*448;
#pragma unroll
    for(int m=0;m<7;m++){ da[lane + 64*m] = c[m].x; da[448 + lane + 64*m] = c[m].y; }
}

// Pass 2 (col pass, packed): 512-thr block = 8 waves, 16 columns (8 pairs) of one image.
// mode=0: grid shear. mode=1: final Sy, b=sin(prm[2]). mode=2: final Ty (b=0, be=prm[1]).
__global__ void __launch_bounds__(512) k_pass2col(
        const float* __restrict__ src, float* __restrict__ dst,
        int rotBase, const float* __restrict__ prm, int mode){
    __shared__ float tile[448][17];
    __shared__ cf WtL[448];
    int tid = threadIdx.x;
    gen_Wt(WtL, tid, 512);
    int rl = blockIdx.x / 28, grp = blockIdx.x % 28;
    int c0 = grp * 16;
    const float* sp = src + (long)rl*IMGN;
#pragma unroll
    for(int i=0;i<14;i++){
        int e = i*512 + tid;
        int r = e >> 4, cc = e & 15;
        tile[r][cc] = sp[(long)r*448 + c0 + cc];
    }
    __syncthreads();
    int w = tid >> 6, lane = tid & 63;
    int ca = c0 + 2*w;
    float b, be;
    if (mode == 1){ b = (float)sin((double)prm[2]); be = 0.f; }
    else if (mode == 2){ b = 0.f; be = prm[1]; }
    else {
        float th = ((float)(rotBase+rl) - 10.f) * 0.017453292519943295f;
        b = sinf(th); be = 0.f;
    }
    float sa = b * ((float)ca - 223.5f) + be;
    float sb = b * ((float)(ca+1) - 223.5f) + be;
    cf c[7];
#pragma unroll
    for(int m=0;m<7;m++){
        int n = lane + 64*m;
        c[m] = make_float2(tile[n][2*w], tile[n][2*w+1]);
    }
    fft448_fwd(c, lane, WtL);
    unpack_phase_repack(c, lane, sa, sb, 0.f, 0.f);
    fft448_inv(c, lane, WtL);
#pragma unroll
    for(int m=0;m<7;m++){
        int n = lane + 64*m;
        tile[n][2*w] = c[m].x; tile[n][2*w+1] = c[m].y;
    }
    __syncthreads();
    float* dp = dst + (long)rl*IMGN;
#pragma unroll
    for(int i=0;i<14;i++){
        int e = i*512 + tid;
        int r = e >> 4, cc = e & 15;
        dp[(long)r*448 + c0 + cc] = tile[r][cc];
    }
}

// Pass 3 (row shear, packed, fresh fwd) -- FINAL WARP ONLY (mode=1 path used).
// mode=1: final SxB with Tx folded (same-axis): non-Nyq summed phase; Nyquist cos*cos.
__global__ void __launch_bounds__(256) k_pass3(
        const float* __restrict__ B, float* __restrict__ A,
        int nrot, int rotBase, const float* __restrict__ prm, int mode){
    __shared__ cf WtL[448];
    gen_Wt(WtL, threadIdx.x, 256);
    __syncthreads();
    int wid = (int)((blockIdx.x*blockDim.x + threadIdx.x) >> 6);
    int lane = threadIdx.x & 63;
    if (wid >= nrot*224) return;
    int rl = wid / 224, rp = wid % 224;
    float a, ga;
    if (mode){ a = (float)(-tan((double)prm[2]*0.5)); ga = prm[0]; }
    else {
        float th = ((float)(rotBase+rl) - 10.f) * 0.017453292519943295f;
        a = -tanf(0.5f*th); ga = 0.f;
    }
    float sa = a * ((float)(2*rp) - 223.5f);
    float sb = a * ((float)(2*rp+1) - 223.5f);
    const float* ra = B + (long)rl*IMGN + (long)(2*rp)*448;
    cf c[7];
#pragma unroll
    for(int m=0;m<7;m++) c[m] = make_float2(ra[lane + 64*m], ra[448 + lane + 64*m]);
    fft448_fwd(c, lane, WtL);
    unpack_phase_repack(c, lane, sa, sb, ga, ga);
    fft448_inv(c, lane, WtL);
    float* da = A + (long)rl*IMGN + (long)(2*rp)*448;
#pragma unroll
    for(int m=0;m<7;m++){ da[lane + 64*m] = c[m].x; da[448 + lane + 64*m] = c[m].y; }
}

// Fused pass3 + SAD. Block = 512 thr (8 waves) handles one (rotation rl, 12-row output tile tt).
// Computes R rows base..base+15 (base = 20+12*tt) via packed row shear into LDS,
// then SAD for output rows 22+12*tt .. min(+11, 424) against img1 with 25 integer rolls.
// partial[combo*34 + tt]; combo = (ix*5 + jy)*21 + rot.
__global__ void __launch_bounds__(512) k_pass3sad(
        const float* __restrict__ B, const float* __restrict__ img1,
        float* __restrict__ partial, int nrot, int rotBase){
    __shared__ float tile[16][448];
    __shared__ cf WtL[448];
    __shared__ float csum[8][25];
    int tid = threadIdx.x;
    gen_Wt(WtL, tid, 512);
    int w = tid >> 6, lane = tid & 63;
    int bid = blockIdx.x;
    int rl = bid / 34, tt = bid % 34;
    int base = 20 + 12*tt;
    float th = ((float)(rotBase+rl) - 10.f) * 0.017453292519943295f;
    float a = -tanf(0.5f*th);
    int rrow = base + 2*w;
    float sa = a * ((float)rrow - 223.5f);
    float sb = a * ((float)(rrow+1) - 223.5f);
    const float* ra = B + (long)rl*IMGN + (long)rrow*448;
    cf c[7];
#pragma unroll
    for(int m=0;m<7;m++) c[m] = make_float2(ra[lane + 64*m], ra[448 + lane + 64*m]);
    __syncthreads();   // WtL ready
    fft448_fwd(c, lane, WtL);
    unpack_phase_repack(c, lane, sa, sb, 0.f, 0.f);
    fft448_inv(c, lane, WtL);
#pragma unroll
    for(int m=0;m<7;m++){
        tile[2*w][lane + 64*m]   = c[m].x;
        tile[2*w+1][lane + 64*m] = c[m].y;
    }
    __syncthreads();
    float acc[25];
#pragma unroll
    for(int q=0;q<25;q++) acc[q] = 0.f;
    int cpos[7];
#pragma unroll
    for(int m=0;m<7;m++) cpos[m] = 22 + lane + 64*m;
#pragma unroll
    for(int pass=0; pass<2; pass++){
        int q = pass*8 + w;
        if (q < 12){
            int r = 22 + 12*tt + q;
            if (r <= 424){
                float iv[7];
#pragma unroll
                for(int m=0;m<7;m++)
                    iv[m] = (cpos[m] < 425) ? img1[(long)r*448 + cpos[m]] : 0.f;
#pragma unroll
                for(int jy=0;jy<5;jy++){
                    const float* Rrow = tile[r - (jy-2) - base];
#pragma unroll
                    for(int ix=0;ix<5;ix++){
                        float s2 = 0.f;
#pragma unroll
                        for(int m=0;m<7;m++){
                            if (cpos[m] < 425) s2 += fabsf(iv[m] - Rrow[cpos[m] - (ix-2)]);
                        }
                        acc[ix*5 + jy] += s2;
                    }
                }
            }
        }
    }
#pragma unroll
    for(int q=0;q<25;q++){
        float v = acc[q];
#pragma unroll
        for(int d=32; d>=1; d>>=1) v += __shfl_xor(v, d, 64);
        if (lane == 0) csum[w][q] = v;
    }
    __syncthreads();
    if (tid < 25){
        float s = 0.f;
#pragma unroll
        for(int ww=0; ww<8; ww++) s += csum[ww][tid];
        int ix = tid/5, jy = tid%5;
        int combo = (ix*5 + jy)*21 + (rotBase + rl);
        partial[(long)combo*34 + tt] = s;
    }
}

extern "C" void kernel_launch(void* const* d_in, const int* in_sizes, int n_in,
                              void* d_out, int out_size, void* d_ws, size_t ws_size,
                              hipStream_t stream){
    const float* img1 = (const float*)d_in[0];
    const float* img2 = (const float*)d_in[1];
    float* out = (float*)d_out;
    char* ws = (char*)d_ws;

    size_t off = 0;
    float* prm = (float*)(ws + off); off += 256;
    float* partial = (float*)(ws + off); off += (size_t)525*34*sizeof(float);
    off = (off + 255) & ~(size_t)255;
    cf* S2 = (cf*)(ws + off); off += (size_t)224*448*sizeof(cf);
    off = (off + 255) & ~(size_t)255;

    size_t slot = (size_t)IMGN * sizeof(float);
    size_t remain = (ws_size > off) ? (ws_size - off) : 0;
    int NB = (int)(remain / (2*slot));
    if (NB > 21) NB = 21;
    if (NB < 2) NB = 2;
    float* A = (float*)(ws + off);
    float* B = (float*)(ws + off + (size_t)NB*slot);

    auto blocks = [](long waves){ return dim3((unsigned)((waves*64 + 255)/256)); };

    hipLaunchKernelGGL(k_prefft, dim3(56), dim3(256), 0, stream, img2, S2);

    for(int rb = 0; rb < 21; rb += NB){
        int nr = (21 - rb < NB) ? (21 - rb) : NB;
        hipLaunchKernelGGL(k_pass1, blocks((long)nr*224), dim3(256), 0, stream,
                           (const cf*)S2, A, nr, rb, prm, 0, (const float*)partial, out);
        hipLaunchKernelGGL(k_pass2col, dim3(nr*28), dim3(512), 0, stream,
                           A, B, rb, prm, 0);
        hipLaunchKernelGGL(k_pass3sad, dim3(nr*34), dim3(512), 0, stream,
                           B, img1, partial, nr, rb);
    }

    // Final sub-pixel warp, 4 packed passes (F1 fuses the finish reduce/argmin):
    //   out = Ty(prm[1]) o [Sx(a*yy) + Tx-fold(prm[0])] o Sy(b*xx) o Sx(a*yy)  on img2
    hipLaunchKernelGGL(k_pass1, blocks(224), dim3(256), 0, stream,
                       (const cf*)S2, A, 1, 0, prm, 1, (const float*)partial, out);
    hipLaunchKernelGGL(k_pass2col, dim3(28), dim3(512), 0, stream,
                       A, B, 0, prm, 1);
    hipLaunchKernelGGL(k_pass3, blocks(224), dim3(256), 0, stream,
                       B, A, 1, 0, prm, 1);
    hipLaunchKernelGGL(k_pass2col, dim3(28), dim3(512), 0, stream,
                       A, out + 3, 0, prm, 2);
}